// Round 1
// baseline (587.463 us; speedup 1.0000x reference)
//
#include <hip/hip_runtime.h>
#include <hip/hip_bf16.h>
#include <math.h>

#define H1 100
#define H2 16
#define FDIM 256

// ---------------- degree histogram / dinv ----------------
__global__ void k_hist(const int* __restrict__ dst, int* __restrict__ deg, int E) {
  int e = blockIdx.x * blockDim.x + threadIdx.x;
  if (e < E) atomicAdd(&deg[dst[e]], 1);
}

__global__ void k_dinv(const int* __restrict__ deg, float* __restrict__ dinv, int n) {
  int i = blockIdx.x * blockDim.x + threadIdx.x;
  if (i < n) dinv[i] = rsqrtf((float)(deg[i] + 1));  // +1 self-loop; always >=1
}

// ---------------- exclusive scan (3-phase) ----------------
__global__ void k_scanA(const int* __restrict__ deg, int* __restrict__ row_ptr,
                        int* __restrict__ psum, int n) {
  __shared__ int s[256];
  int tid = threadIdx.x;
  int i = blockIdx.x * 256 + tid;
  int v = (i < n) ? deg[i] : 0;
  s[tid] = v;
  __syncthreads();
  for (int off = 1; off < 256; off <<= 1) {
    int t = (tid >= off) ? s[tid - off] : 0;
    __syncthreads();
    s[tid] += t;
    __syncthreads();
  }
  if (i < n) row_ptr[i] = s[tid] - v;           // exclusive within block
  if (tid == 255) psum[blockIdx.x] = s[255];    // block total
}

__global__ void k_scanB(int* psum, int nb) {
  __shared__ int s[512];
  int tid = threadIdx.x;
  int v = (tid < nb) ? psum[tid] : 0;
  s[tid] = v;
  __syncthreads();
  for (int off = 1; off < 512; off <<= 1) {
    int t = (tid >= off) ? s[tid - off] : 0;
    __syncthreads();
    s[tid] += t;
    __syncthreads();
  }
  if (tid < nb) psum[tid] = s[tid] - v;         // exclusive block offsets
}

__global__ void k_scanC(int* row_ptr, const int* __restrict__ psum, int n, int E) {
  int i = blockIdx.x * blockDim.x + threadIdx.x;
  if (i < n) row_ptr[i] += psum[i >> 8];
  if (i == 0) row_ptr[n] = E;
}

// ---------------- CSR scatter ----------------
__global__ void k_scatter(const int* __restrict__ src, const int* __restrict__ dst,
                          const int* __restrict__ row_ptr, int* __restrict__ fill,
                          int* __restrict__ col_src, int E) {
  int e = blockIdx.x * blockDim.x + threadIdx.x;
  if (e >= E) return;
  int d = dst[e];
  int pos = row_ptr[d] + atomicAdd(&fill[d], 1);
  col_src[pos] = src[e];
}

// ---------------- GEMM1: t1p = (x @ W1) * dinv[row]  (N x 256 x 100) --------
// 320 threads = 5 waves; wave wv owns cols [wv*20, wv*20+20); lane owns rows
// {l, l+64, l+128, l+192} of a 256-row tile. acc[4][20] in regs.
__global__ __launch_bounds__(320)
void k_gemm1(const float* __restrict__ x, const float* __restrict__ W1,
             const float* __restrict__ dinv, float* __restrict__ t1p, int n) {
  __shared__ float xs[256][33];                  // pad 33: conflict-free a-reads
  __shared__ alignas(16) float wsm[32][100];     // k-tile x cols
  int tid = threadIdx.x;
  int lane = tid & 63;
  int wv = tid >> 6;                             // 0..4
  int r0 = blockIdx.x * 256;

  float acc[4][20];
#pragma unroll
  for (int q = 0; q < 4; q++)
#pragma unroll
    for (int j = 0; j < 20; j++) acc[q][j] = 0.f;

  for (int k0 = 0; k0 < FDIM; k0 += 32) {
    // stage x tile: 256 rows x 32 k  (2048 float4)
    for (int idx = tid; idx < 2048; idx += 320) {
      int row = idx >> 3, c4 = idx & 7;
      int gr = r0 + row;
      float4 v = make_float4(0.f, 0.f, 0.f, 0.f);
      if (gr < n) v = *(const float4*)(x + (size_t)gr * FDIM + k0 + c4 * 4);
      xs[row][c4 * 4 + 0] = v.x;
      xs[row][c4 * 4 + 1] = v.y;
      xs[row][c4 * 4 + 2] = v.z;
      xs[row][c4 * 4 + 3] = v.w;
    }
    // stage W tile: 32 k x 100 cols (800 float4)
    for (int idx = tid; idx < 800; idx += 320) {
      int k = idx / 25, c4 = idx % 25;
      float4 v = *(const float4*)(W1 + (size_t)(k0 + k) * H1 + c4 * 4);
      *(float4*)&wsm[k][c4 * 4] = v;
    }
    __syncthreads();
#pragma unroll 2
    for (int k = 0; k < 32; ++k) {
      float a0 = xs[lane][k];
      float a1 = xs[lane + 64][k];
      float a2 = xs[lane + 128][k];
      float a3 = xs[lane + 192][k];
#pragma unroll
      for (int j5 = 0; j5 < 5; j5++) {
        float4 w = *(const float4*)&wsm[k][wv * 20 + 4 * j5];
        acc[0][4 * j5 + 0] += a0 * w.x; acc[0][4 * j5 + 1] += a0 * w.y;
        acc[0][4 * j5 + 2] += a0 * w.z; acc[0][4 * j5 + 3] += a0 * w.w;
        acc[1][4 * j5 + 0] += a1 * w.x; acc[1][4 * j5 + 1] += a1 * w.y;
        acc[1][4 * j5 + 2] += a1 * w.z; acc[1][4 * j5 + 3] += a1 * w.w;
        acc[2][4 * j5 + 0] += a2 * w.x; acc[2][4 * j5 + 1] += a2 * w.y;
        acc[2][4 * j5 + 2] += a2 * w.z; acc[2][4 * j5 + 3] += a2 * w.w;
        acc[3][4 * j5 + 0] += a3 * w.x; acc[3][4 * j5 + 1] += a3 * w.y;
        acc[3][4 * j5 + 2] += a3 * w.z; acc[3][4 * j5 + 3] += a3 * w.w;
      }
    }
    __syncthreads();
  }
#pragma unroll
  for (int q = 0; q < 4; q++) {
    int gr = r0 + lane + 64 * q;
    if (gr < n) {
      float dv = dinv[gr];
#pragma unroll
      for (int j5 = 0; j5 < 5; j5++) {
        float4 o = make_float4(acc[q][4 * j5 + 0] * dv, acc[q][4 * j5 + 1] * dv,
                               acc[q][4 * j5 + 2] * dv, acc[q][4 * j5 + 3] * dv);
        *(float4*)(t1p + (size_t)gr * H1 + wv * 20 + 4 * j5) = o;
      }
    }
  }
}

// ---------------- agg1: h[d] = relu(dinv[d]*(sum t1p[s] + t1p[d]) + b1) -----
// one wave per node; lane c and c+64 cover 100 cols.
__global__ __launch_bounds__(256)
void k_agg1(const float* __restrict__ t1p, const int* __restrict__ row_ptr,
            const int* __restrict__ col_src, const float* __restrict__ dinv,
            const float* __restrict__ b1, float* __restrict__ h, int n) {
  int wid = (int)((blockIdx.x * (size_t)blockDim.x + threadIdx.x) >> 6);
  if (wid >= n) return;
  int lane = threadIdx.x & 63;
  int d = wid;
  int beg = row_ptr[d], end = row_ptr[d + 1];
  int c1 = lane + 64;
  bool has2 = (c1 < H1);
  float acc0 = 0.f, acc1 = 0.f;
  for (int e = beg; e < end; ++e) {
    int s = col_src[e];
    const float* row = t1p + (size_t)s * H1;
    acc0 += row[lane];
    if (has2) acc1 += row[c1];
  }
  const float* selfrow = t1p + (size_t)d * H1;
  acc0 += selfrow[lane];
  if (has2) acc1 += selfrow[c1];
  float dv = dinv[d];
  h[(size_t)d * H1 + lane] = fmaxf(dv * acc0 + b1[lane], 0.f);
  if (has2) h[(size_t)d * H1 + c1] = fmaxf(dv * acc1 + b1[c1], 0.f);
}

// ---------------- GEMM2: t2p = (h @ W2) * dinv  (N x 100 x 16) --------------
__global__ __launch_bounds__(256)
void k_gemm2(const float* __restrict__ h, const float* __restrict__ W2,
             const float* __restrict__ dinv, float* __restrict__ t2p, int n) {
  __shared__ alignas(16) float w2s[100][16];
  __shared__ float hs[64][101];
  int tid = threadIdx.x;
  int r0 = blockIdx.x * 64;
  for (int idx = tid; idx < H1 * H2; idx += 256) w2s[idx / 16][idx % 16] = W2[idx];
  for (int idx = tid; idx < 64 * 25; idx += 256) {
    int row = idx / 25, c4 = idx % 25;
    int gr = r0 + row;
    float4 v = make_float4(0.f, 0.f, 0.f, 0.f);
    if (gr < n) v = *(const float4*)(h + (size_t)gr * H1 + c4 * 4);
    hs[row][c4 * 4 + 0] = v.x; hs[row][c4 * 4 + 1] = v.y;
    hs[row][c4 * 4 + 2] = v.z; hs[row][c4 * 4 + 3] = v.w;
  }
  __syncthreads();
  int r = tid & 63, cg = tid >> 6;
  float ax = 0.f, ay = 0.f, az = 0.f, aw = 0.f;
#pragma unroll 4
  for (int k = 0; k < H1; ++k) {
    float a = hs[r][k];
    float4 w = *(const float4*)&w2s[k][cg * 4];
    ax += a * w.x; ay += a * w.y; az += a * w.z; aw += a * w.w;
  }
  int gr = r0 + r;
  if (gr < n) {
    float dv = dinv[gr];
    float4 o = make_float4(ax * dv, ay * dv, az * dv, aw * dv);
    *(float4*)(t2p + (size_t)gr * H2 + cg * 4) = o;
  }
}

// ------- agg2 + bias + relu + row-normalize: emb (N x 16) -------------------
// wave per node: lane = es*16 + c  (4 edge slots x 16 cols)
__global__ __launch_bounds__(256)
void k_agg2(const float* __restrict__ t2p, const int* __restrict__ row_ptr,
            const int* __restrict__ col_src, const float* __restrict__ dinv,
            const float* __restrict__ b2, float* __restrict__ emb, int n) {
  int wid = (int)((blockIdx.x * (size_t)blockDim.x + threadIdx.x) >> 6);
  if (wid >= n) return;
  int lane = threadIdx.x & 63;
  int es = lane >> 4, c = lane & 15;
  int d = wid;
  int beg = row_ptr[d], end = row_ptr[d + 1];
  float acc = 0.f;
  for (int e = beg + es; e < end; e += 4) {
    int s = col_src[e];
    acc += t2p[(size_t)s * H2 + c];
  }
  acc += __shfl_xor(acc, 16, 64);
  acc += __shfl_xor(acc, 32, 64);
  acc += t2p[(size_t)d * H2 + c];
  float v = fmaxf(dinv[d] * acc + b2[c], 0.f);
  float n2 = v * v;
  n2 += __shfl_xor(n2, 1, 64);
  n2 += __shfl_xor(n2, 2, 64);
  n2 += __shfl_xor(n2, 4, 64);
  n2 += __shfl_xor(n2, 8, 64);
  float scale = 1.f / fmaxf(sqrtf(n2), 1.f);
  if (lane < 16) emb[(size_t)d * H2 + c] = v * scale;
}

// ---------------- edge scorer ------------------------------------------------
__global__ __launch_bounds__(256)
void k_score(const float* __restrict__ emb, const int* __restrict__ te,
             const float* __restrict__ PI, const float* __restrict__ l1W,
             const float* __restrict__ l1b, const float* __restrict__ lW,
             const float* __restrict__ lb, float* __restrict__ out, int ned) {
  __shared__ alignas(16) float wT[25][44];  // transposed lin1_W
  __shared__ float sb1[25], sw2[25];
  for (int idx = threadIdx.x; idx < 41 * 25; idx += blockDim.x) {
    int i = idx / 25, j = idx % 25;
    wT[j][i] = l1W[idx];
  }
  for (int idx = threadIdx.x; idx < 25; idx += blockDim.x) {
    sb1[idx] = l1b[idx];
    sw2[idx] = lW[idx];
  }
  __syncthreads();
  int e = blockIdx.x * blockDim.x + threadIdx.x;
  if (e >= ned) return;
  int u = te[2 * e], v = te[2 * e + 1];
  float f[41];
  const float4* eu = (const float4*)(emb + (size_t)u * H2);
  const float4* ev = (const float4*)(emb + (size_t)v * H2);
#pragma unroll
  for (int q = 0; q < 4; q++) {
    float4 a = eu[q], b = ev[q];
    float dx = a.x - b.x, dy = a.y - b.y, dz = a.z - b.z, dw = a.w - b.w;
    f[q * 4 + 0] = dx * dx; f[q * 4 + 1] = dy * dy;
    f[q * 4 + 2] = dz * dz; f[q * 4 + 3] = dw * dw;
  }
  const float* pi = PI + (size_t)e * 25;
#pragma unroll
  for (int i = 0; i < 25; i++) f[16 + i] = pi[i];
  float acc2 = lb[0];
  for (int j = 0; j < 25; j++) {
    float a = sb1[j];
#pragma unroll
    for (int i = 0; i < 41; i++) a += f[i] * wT[j][i];
    a = (a > 0.f) ? a : 0.2f * a;           // leaky relu 0.2
    acc2 += a * sw2[j];
  }
  float s = fminf(fabsf(acc2), 40.f);
  float z = 2.f - s;
  out[e] = 1.f / (1.f + __expf(-z));
}

// ---------------- launch -----------------------------------------------------
extern "C" void kernel_launch(void* const* d_in, const int* in_sizes, int n_in,
                              void* d_out, int out_size, void* d_ws, size_t ws_size,
                              hipStream_t stream) {
  const float* x   = (const float*)d_in[0];
  const int*   ei  = (const int*)d_in[1];
  const int*   te  = (const int*)d_in[2];
  const float* PI  = (const float*)d_in[3];
  const float* W1  = (const float*)d_in[4];
  const float* b1  = (const float*)d_in[5];
  const float* W2  = (const float*)d_in[6];
  const float* b2  = (const float*)d_in[7];
  const float* l1W = (const float*)d_in[8];
  const float* l1b = (const float*)d_in[9];
  const float* lW  = (const float*)d_in[10];
  const float* lb  = (const float*)d_in[11];
  float* out = (float*)d_out;

  int h1 = in_sizes[5];            // 100
  int F  = in_sizes[4] / h1;       // 256
  int N  = in_sizes[0] / F;        // 100000
  int E  = in_sizes[1] / 2;        // 1600000
  int ED = in_sizes[2] / 2;        // 1000000

  const int* src  = ei;
  const int* dstp = ei + E;

  size_t off = 0;
  auto alloc = [&](size_t bytes) -> void* {
    void* p = (char*)d_ws + off;
    off += (bytes + 255) & ~(size_t)255;
    return p;
  };
  int*   deg     = (int*)alloc((size_t)N * 4);
  float* dinv    = (float*)alloc((size_t)N * 4);
  int*   row_ptr = (int*)alloc((size_t)(N + 1) * 4);
  int*   fill    = (int*)alloc((size_t)N * 4);
  int*   psum    = (int*)alloc(512 * 4);
  int*   col_src = (int*)alloc((size_t)E * 4);
  float* t1p     = (float*)alloc((size_t)N * H1 * 4);
  float* h       = (float*)alloc((size_t)N * H1 * 4);
  float* t2p     = (float*)alloc((size_t)N * H2 * 4);
  float* emb     = (float*)alloc((size_t)N * H2 * 4);

  int nb = (N + 255) / 256;

  hipMemsetAsync(deg, 0, (size_t)N * 4, stream);
  k_hist<<<(E + 255) / 256, 256, 0, stream>>>(dstp, deg, E);
  k_dinv<<<(N + 255) / 256, 256, 0, stream>>>(deg, dinv, N);
  k_scanA<<<nb, 256, 0, stream>>>(deg, row_ptr, psum, N);
  k_scanB<<<1, 512, 0, stream>>>(psum, nb);
  k_scanC<<<nb, 256, 0, stream>>>(row_ptr, psum, N, E);
  hipMemsetAsync(fill, 0, (size_t)N * 4, stream);
  k_scatter<<<(E + 255) / 256, 256, 0, stream>>>(src, dstp, row_ptr, fill, col_src, E);
  k_gemm1<<<(N + 255) / 256, 320, 0, stream>>>(x, W1, dinv, t1p, N);
  k_agg1<<<(int)(((size_t)N * 64 + 255) / 256), 256, 0, stream>>>(t1p, row_ptr, col_src, dinv, b1, h, N);
  k_gemm2<<<(N + 63) / 64, 256, 0, stream>>>(h, W2, dinv, t2p, N);
  k_agg2<<<(int)(((size_t)N * 64 + 255) / 256), 256, 0, stream>>>(t2p, row_ptr, col_src, dinv, b2, emb, N);
  k_score<<<(ED + 255) / 256, 256, 0, stream>>>(emb, te, PI, l1W, l1b, lW, lb, out, ED);
}

// Round 2
// 569.993 us; speedup vs baseline: 1.0306x; 1.0306x over previous
//
#include <hip/hip_runtime.h>
#include <hip/hip_bf16.h>
#include <math.h>

#define H1 100
#define H2 16
#define FDIM 256

// ---- bf16 pack/unpack helpers (bit-exact unpack, RNE pack) ----
__device__ __forceinline__ float bf_lo(unsigned u) { return __uint_as_float(u << 16); }
__device__ __forceinline__ float bf_hi(unsigned u) { return __uint_as_float(u & 0xffff0000u); }
__device__ __forceinline__ unsigned f2bf_bits(float f) {
  unsigned x = __float_as_uint(f);
  return (x + 0x7fffu + ((x >> 16) & 1u)) >> 16;   // round-nearest-even
}
__device__ __forceinline__ unsigned pack_bf16(float a, float b) {
  return f2bf_bits(a) | (f2bf_bits(b) << 16);
}

// ---------------- degree histogram / dinv ----------------
__global__ void k_hist(const int* __restrict__ dst, int* __restrict__ deg, int E) {
  int e = blockIdx.x * blockDim.x + threadIdx.x;
  if (e < E) atomicAdd(&deg[dst[e]], 1);
}

__global__ void k_dinv(const int* __restrict__ deg, float* __restrict__ dinv, int n) {
  int i = blockIdx.x * blockDim.x + threadIdx.x;
  if (i < n) dinv[i] = rsqrtf((float)(deg[i] + 1));  // +1 self-loop
}

// ---------------- exclusive scan (3-phase) ----------------
__global__ void k_scanA(const int* __restrict__ deg, int* __restrict__ row_ptr,
                        int* __restrict__ psum, int n) {
  __shared__ int s[256];
  int tid = threadIdx.x;
  int i = blockIdx.x * 256 + tid;
  int v = (i < n) ? deg[i] : 0;
  s[tid] = v;
  __syncthreads();
  for (int off = 1; off < 256; off <<= 1) {
    int t = (tid >= off) ? s[tid - off] : 0;
    __syncthreads();
    s[tid] += t;
    __syncthreads();
  }
  if (i < n) row_ptr[i] = s[tid] - v;
  if (tid == 255) psum[blockIdx.x] = s[255];
}

__global__ void k_scanB(int* psum, int nb) {
  __shared__ int s[512];
  int tid = threadIdx.x;
  int v = (tid < nb) ? psum[tid] : 0;
  s[tid] = v;
  __syncthreads();
  for (int off = 1; off < 512; off <<= 1) {
    int t = (tid >= off) ? s[tid - off] : 0;
    __syncthreads();
    s[tid] += t;
    __syncthreads();
  }
  if (tid < nb) psum[tid] = s[tid] - v;
}

__global__ void k_scanC(int* row_ptr, const int* __restrict__ psum, int n, int E) {
  int i = blockIdx.x * blockDim.x + threadIdx.x;
  if (i < n) row_ptr[i] += psum[i >> 8];
  if (i == 0) row_ptr[n] = E;
}

// ---------------- CSR scatter ----------------
__global__ void k_scatter(const int* __restrict__ src, const int* __restrict__ dst,
                          const int* __restrict__ row_ptr, int* __restrict__ fill,
                          int* __restrict__ col_src, int E) {
  int e = blockIdx.x * blockDim.x + threadIdx.x;
  if (e >= E) return;
  int d = dst[e];
  int pos = row_ptr[d] + atomicAdd(&fill[d], 1);
  col_src[pos] = src[e];
}

// ------ GEMM1: t1p = bf16( (x @ W1) * dinv[row] )  (N x 256 x 100) ----------
__global__ __launch_bounds__(320)
void k_gemm1(const float* __restrict__ x, const float* __restrict__ W1,
             const float* __restrict__ dinv, unsigned* __restrict__ t1p, int n) {
  __shared__ float xs[256][33];
  __shared__ alignas(16) float wsm[32][100];
  int tid = threadIdx.x;
  int lane = tid & 63;
  int wv = tid >> 6;                             // 0..4
  int r0 = blockIdx.x * 256;

  float acc[4][20];
#pragma unroll
  for (int q = 0; q < 4; q++)
#pragma unroll
    for (int j = 0; j < 20; j++) acc[q][j] = 0.f;

  for (int k0 = 0; k0 < FDIM; k0 += 32) {
    for (int idx = tid; idx < 2048; idx += 320) {
      int row = idx >> 3, c4 = idx & 7;
      int gr = r0 + row;
      float4 v = make_float4(0.f, 0.f, 0.f, 0.f);
      if (gr < n) v = *(const float4*)(x + (size_t)gr * FDIM + k0 + c4 * 4);
      xs[row][c4 * 4 + 0] = v.x;
      xs[row][c4 * 4 + 1] = v.y;
      xs[row][c4 * 4 + 2] = v.z;
      xs[row][c4 * 4 + 3] = v.w;
    }
    for (int idx = tid; idx < 800; idx += 320) {
      int k = idx / 25, c4 = idx % 25;
      float4 v = *(const float4*)(W1 + (size_t)(k0 + k) * H1 + c4 * 4);
      *(float4*)&wsm[k][c4 * 4] = v;
    }
    __syncthreads();
#pragma unroll 2
    for (int k = 0; k < 32; ++k) {
      float a0 = xs[lane][k];
      float a1 = xs[lane + 64][k];
      float a2 = xs[lane + 128][k];
      float a3 = xs[lane + 192][k];
#pragma unroll
      for (int j5 = 0; j5 < 5; j5++) {
        float4 w = *(const float4*)&wsm[k][wv * 20 + 4 * j5];
        acc[0][4 * j5 + 0] += a0 * w.x; acc[0][4 * j5 + 1] += a0 * w.y;
        acc[0][4 * j5 + 2] += a0 * w.z; acc[0][4 * j5 + 3] += a0 * w.w;
        acc[1][4 * j5 + 0] += a1 * w.x; acc[1][4 * j5 + 1] += a1 * w.y;
        acc[1][4 * j5 + 2] += a1 * w.z; acc[1][4 * j5 + 3] += a1 * w.w;
        acc[2][4 * j5 + 0] += a2 * w.x; acc[2][4 * j5 + 1] += a2 * w.y;
        acc[2][4 * j5 + 2] += a2 * w.z; acc[2][4 * j5 + 3] += a2 * w.w;
        acc[3][4 * j5 + 0] += a3 * w.x; acc[3][4 * j5 + 1] += a3 * w.y;
        acc[3][4 * j5 + 2] += a3 * w.z; acc[3][4 * j5 + 3] += a3 * w.w;
      }
    }
    __syncthreads();
  }
#pragma unroll
  for (int q = 0; q < 4; q++) {
    int gr = r0 + lane + 64 * q;
    if (gr < n) {
      float dv = dinv[gr];
#pragma unroll
      for (int j = 0; j < 10; j++) {
        t1p[(size_t)gr * 50 + wv * 10 + j] =
            pack_bf16(acc[q][2 * j] * dv, acc[q][2 * j + 1] * dv);
      }
    }
  }
}

// ---- agg1: h[d] = bf16(relu(dinv[d]*(sum t1p[s] + t1p[d]) + b1)) -----------
// wave per node; lanes 0..49 each own 2 cols (one packed uint).
__global__ __launch_bounds__(256)
void k_agg1(const unsigned* __restrict__ t1p, const int* __restrict__ row_ptr,
            const int* __restrict__ col_src, const float* __restrict__ dinv,
            const float* __restrict__ b1, unsigned* __restrict__ h, int n) {
  int wid = (int)((blockIdx.x * (size_t)blockDim.x + threadIdx.x) >> 6);
  if (wid >= n) return;
  int lane = threadIdx.x & 63;
  if (lane >= 50) return;
  int beg = row_ptr[wid], end = row_ptr[wid + 1];
  float a0 = 0.f, a1 = 0.f;
  for (int e = beg; e < end; ++e) {
    int s = col_src[e];
    unsigned u = t1p[(size_t)s * 50 + lane];
    a0 += bf_lo(u);
    a1 += bf_hi(u);
  }
  unsigned su = t1p[(size_t)wid * 50 + lane];
  a0 += bf_lo(su);
  a1 += bf_hi(su);
  float dv = dinv[wid];
  float v0 = fmaxf(dv * a0 + b1[2 * lane], 0.f);
  float v1 = fmaxf(dv * a1 + b1[2 * lane + 1], 0.f);
  h[(size_t)wid * 50 + lane] = pack_bf16(v0, v1);
}

// ------ GEMM2: t2p = bf16( (h @ W2) * dinv )  (N x 100 x 16) ----------------
__global__ __launch_bounds__(256)
void k_gemm2(const unsigned* __restrict__ h, const float* __restrict__ W2,
             const float* __restrict__ dinv, unsigned* __restrict__ t2p, int n) {
  __shared__ alignas(16) float w2s[100][16];
  __shared__ float hs[64][101];
  int tid = threadIdx.x;
  int r0 = blockIdx.x * 64;
  for (int idx = tid; idx < H1 * H2; idx += 256) w2s[idx / 16][idx % 16] = W2[idx];
  for (int idx = tid; idx < 64 * 50; idx += 256) {
    int row = idx / 50, u = idx % 50;
    int gr = r0 + row;
    unsigned v = 0;
    if (gr < n) v = h[(size_t)gr * 50 + u];
    hs[row][2 * u + 0] = bf_lo(v);
    hs[row][2 * u + 1] = bf_hi(v);
  }
  __syncthreads();
  int r = tid & 63, cg = tid >> 6;
  float ax = 0.f, ay = 0.f, az = 0.f, aw = 0.f;
#pragma unroll 4
  for (int k = 0; k < H1; ++k) {
    float a = hs[r][k];
    float4 w = *(const float4*)&w2s[k][cg * 4];
    ax += a * w.x; ay += a * w.y; az += a * w.z; aw += a * w.w;
  }
  int gr = r0 + r;
  if (gr < n) {
    float dv = dinv[gr];
    unsigned u0 = pack_bf16(ax * dv, ay * dv);
    unsigned u1 = pack_bf16(az * dv, aw * dv);
    *(uint2*)(t2p + (size_t)gr * 8 + cg * 2) = make_uint2(u0, u1);
  }
}

// ------- agg2 + bias + relu + row-normalize: emb (N x 16, f32) --------------
// wave per node: lane = es*8 + c  (8 edge slots x 8 packed-col slots)
__global__ __launch_bounds__(256)
void k_agg2(const unsigned* __restrict__ t2p, const int* __restrict__ row_ptr,
            const int* __restrict__ col_src, const float* __restrict__ dinv,
            const float* __restrict__ b2, float* __restrict__ emb, int n) {
  int wid = (int)((blockIdx.x * (size_t)blockDim.x + threadIdx.x) >> 6);
  if (wid >= n) return;
  int lane = threadIdx.x & 63;
  int es = lane >> 3, c = lane & 7;
  int beg = row_ptr[wid], end = row_ptr[wid + 1];
  float a0 = 0.f, a1 = 0.f;
  for (int e = beg + es; e < end; e += 8) {
    int s = col_src[e];
    unsigned u = t2p[(size_t)s * 8 + c];
    a0 += bf_lo(u);
    a1 += bf_hi(u);
  }
  a0 += __shfl_xor(a0, 8, 64);  a1 += __shfl_xor(a1, 8, 64);
  a0 += __shfl_xor(a0, 16, 64); a1 += __shfl_xor(a1, 16, 64);
  a0 += __shfl_xor(a0, 32, 64); a1 += __shfl_xor(a1, 32, 64);
  unsigned su = t2p[(size_t)wid * 8 + c];
  a0 += bf_lo(su);
  a1 += bf_hi(su);
  float dv = dinv[wid];
  float v0 = fmaxf(dv * a0 + b2[2 * c + 0], 0.f);
  float v1 = fmaxf(dv * a1 + b2[2 * c + 1], 0.f);
  float n2 = v0 * v0 + v1 * v1;
  n2 += __shfl_xor(n2, 1, 64);
  n2 += __shfl_xor(n2, 2, 64);
  n2 += __shfl_xor(n2, 4, 64);
  float scale = 1.f / fmaxf(sqrtf(n2), 1.f);
  if (es == 0) {
    *(float2*)(emb + (size_t)wid * H2 + 2 * c) = make_float2(v0 * scale, v1 * scale);
  }
}

// ---------------- edge scorer ------------------------------------------------
__global__ __launch_bounds__(256)
void k_score(const float* __restrict__ emb, const int* __restrict__ te,
             const float* __restrict__ PI, const float* __restrict__ l1W,
             const float* __restrict__ l1b, const float* __restrict__ lW,
             const float* __restrict__ lb, float* __restrict__ out, int ned) {
  __shared__ alignas(16) float wT[25][44];
  __shared__ float sb1[25], sw2[25];
  for (int idx = threadIdx.x; idx < 41 * 25; idx += blockDim.x) {
    int i = idx / 25, j = idx % 25;
    wT[j][i] = l1W[idx];
  }
  for (int idx = threadIdx.x; idx < 25; idx += blockDim.x) {
    sb1[idx] = l1b[idx];
    sw2[idx] = lW[idx];
  }
  __syncthreads();
  int e = blockIdx.x * blockDim.x + threadIdx.x;
  if (e >= ned) return;
  int u = te[2 * e], v = te[2 * e + 1];
  float f[41];
  const float4* eu = (const float4*)(emb + (size_t)u * H2);
  const float4* ev = (const float4*)(emb + (size_t)v * H2);
#pragma unroll
  for (int q = 0; q < 4; q++) {
    float4 a = eu[q], b = ev[q];
    float dx = a.x - b.x, dy = a.y - b.y, dz = a.z - b.z, dw = a.w - b.w;
    f[q * 4 + 0] = dx * dx; f[q * 4 + 1] = dy * dy;
    f[q * 4 + 2] = dz * dz; f[q * 4 + 3] = dw * dw;
  }
  const float* pi = PI + (size_t)e * 25;
#pragma unroll
  for (int i = 0; i < 25; i++) f[16 + i] = pi[i];
  float acc2 = lb[0];
  for (int j = 0; j < 25; j++) {
    float a = sb1[j];
#pragma unroll
    for (int i = 0; i < 41; i++) a += f[i] * wT[j][i];
    a = (a > 0.f) ? a : 0.2f * a;
    acc2 += a * sw2[j];
  }
  float s = fminf(fabsf(acc2), 40.f);
  float z = 2.f - s;
  out[e] = 1.f / (1.f + __expf(-z));
}

// ---------------- launch -----------------------------------------------------
extern "C" void kernel_launch(void* const* d_in, const int* in_sizes, int n_in,
                              void* d_out, int out_size, void* d_ws, size_t ws_size,
                              hipStream_t stream) {
  const float* x   = (const float*)d_in[0];
  const int*   ei  = (const int*)d_in[1];
  const int*   te  = (const int*)d_in[2];
  const float* PI  = (const float*)d_in[3];
  const float* W1  = (const float*)d_in[4];
  const float* b1  = (const float*)d_in[5];
  const float* W2  = (const float*)d_in[6];
  const float* b2  = (const float*)d_in[7];
  const float* l1W = (const float*)d_in[8];
  const float* l1b = (const float*)d_in[9];
  const float* lW  = (const float*)d_in[10];
  const float* lb  = (const float*)d_in[11];
  float* out = (float*)d_out;

  int h1 = in_sizes[5];            // 100
  int F  = in_sizes[4] / h1;       // 256
  int N  = in_sizes[0] / F;        // 100000
  int E  = in_sizes[1] / 2;        // 1600000
  int ED = in_sizes[2] / 2;        // 1000000

  const int* src  = ei;
  const int* dstp = ei + E;

  size_t off = 0;
  auto alloc = [&](size_t bytes) -> void* {
    void* p = (char*)d_ws + off;
    off += (bytes + 255) & ~(size_t)255;
    return p;
  };
  int*      deg     = (int*)alloc((size_t)N * 4);
  float*    dinv    = (float*)alloc((size_t)N * 4);
  int*      row_ptr = (int*)alloc((size_t)(N + 1) * 4);
  int*      fill    = (int*)alloc((size_t)N * 4);
  int*      psum    = (int*)alloc(512 * 4);
  int*      col_src = (int*)alloc((size_t)E * 4);
  unsigned* t1p     = (unsigned*)alloc((size_t)N * 50 * 4);  // bf16 x2 packed
  unsigned* h       = (unsigned*)alloc((size_t)N * 50 * 4);
  unsigned* t2p     = (unsigned*)alloc((size_t)N * 8 * 4);
  float*    emb     = (float*)alloc((size_t)N * H2 * 4);

  int nb = (N + 255) / 256;

  hipMemsetAsync(deg, 0, (size_t)N * 4, stream);
  k_hist<<<(E + 255) / 256, 256, 0, stream>>>(dstp, deg, E);
  k_dinv<<<(N + 255) / 256, 256, 0, stream>>>(deg, dinv, N);
  k_scanA<<<nb, 256, 0, stream>>>(deg, row_ptr, psum, N);
  k_scanB<<<1, 512, 0, stream>>>(psum, nb);
  k_scanC<<<nb, 256, 0, stream>>>(row_ptr, psum, N, E);
  hipMemsetAsync(fill, 0, (size_t)N * 4, stream);
  k_scatter<<<(E + 255) / 256, 256, 0, stream>>>(src, dstp, row_ptr, fill, col_src, E);
  k_gemm1<<<(N + 255) / 256, 320, 0, stream>>>(x, W1, dinv, t1p, N);
  k_agg1<<<(int)(((size_t)N * 64 + 255) / 256), 256, 0, stream>>>(t1p, row_ptr, col_src, dinv, b1, h, N);
  k_gemm2<<<(N + 63) / 64, 256, 0, stream>>>(h, W2, dinv, t2p, N);
  k_agg2<<<(int)(((size_t)N * 64 + 255) / 256), 256, 0, stream>>>(t2p, row_ptr, col_src, dinv, b2, emb, N);
  k_score<<<(ED + 255) / 256, 256, 0, stream>>>(emb, te, PI, l1W, l1b, lW, lb, out, ED);
}

// Round 3
// 399.569 us; speedup vs baseline: 1.4702x; 1.4265x over previous
//
#include <hip/hip_runtime.h>
#include <hip/hip_bf16.h>
#include <math.h>

#define H1 100
#define H2 16
#define FDIM 256
#define NPAD 112   // H1 padded to 7*16

typedef __attribute__((ext_vector_type(8))) short bf16x8;
typedef __attribute__((ext_vector_type(4))) float f32x4;

// ---- bf16 pack/unpack helpers (bit-exact unpack, RNE pack) ----
__device__ __forceinline__ float bf_lo(unsigned u) { return __uint_as_float(u << 16); }
__device__ __forceinline__ float bf_hi(unsigned u) { return __uint_as_float(u & 0xffff0000u); }
__device__ __forceinline__ unsigned f2bf_bits(float f) {
  unsigned x = __float_as_uint(f);
  return (x + 0x7fffu + ((x >> 16) & 1u)) >> 16;   // round-nearest-even
}
__device__ __forceinline__ unsigned pack_bf16(float a, float b) {
  return f2bf_bits(a) | (f2bf_bits(b) << 16);
}

// ---------------- degree histogram / dinv ----------------
__global__ void k_hist(const int* __restrict__ dst, int* __restrict__ deg, int E) {
  int e = blockIdx.x * blockDim.x + threadIdx.x;
  if (e < E) atomicAdd(&deg[dst[e]], 1);
}

__global__ void k_dinv(const int* __restrict__ deg, float* __restrict__ dinv, int n) {
  int i = blockIdx.x * blockDim.x + threadIdx.x;
  if (i < n) dinv[i] = rsqrtf((float)(deg[i] + 1));  // +1 self-loop
}

// ---------------- exclusive scan (3-phase) ----------------
__global__ void k_scanA(const int* __restrict__ deg, int* __restrict__ row_ptr,
                        int* __restrict__ psum, int n) {
  __shared__ int s[256];
  int tid = threadIdx.x;
  int i = blockIdx.x * 256 + tid;
  int v = (i < n) ? deg[i] : 0;
  s[tid] = v;
  __syncthreads();
  for (int off = 1; off < 256; off <<= 1) {
    int t = (tid >= off) ? s[tid - off] : 0;
    __syncthreads();
    s[tid] += t;
    __syncthreads();
  }
  if (i < n) row_ptr[i] = s[tid] - v;
  if (tid == 255) psum[blockIdx.x] = s[255];
}

__global__ void k_scanB(int* psum, int nb) {
  __shared__ int s[512];
  int tid = threadIdx.x;
  int v = (tid < nb) ? psum[tid] : 0;
  s[tid] = v;
  __syncthreads();
  for (int off = 1; off < 512; off <<= 1) {
    int t = (tid >= off) ? s[tid - off] : 0;
    __syncthreads();
    s[tid] += t;
    __syncthreads();
  }
  if (tid < nb) psum[tid] = s[tid] - v;
}

__global__ void k_scanC(int* row_ptr, const int* __restrict__ psum, int n, int E) {
  int i = blockIdx.x * blockDim.x + threadIdx.x;
  if (i < n) row_ptr[i] += psum[i >> 8];
  if (i == 0) row_ptr[n] = E;
}

// ---------------- CSR scatter ----------------
__global__ void k_scatter(const int* __restrict__ src, const int* __restrict__ dst,
                          const int* __restrict__ row_ptr, int* __restrict__ fill,
                          int* __restrict__ col_src, int E) {
  int e = blockIdx.x * blockDim.x + threadIdx.x;
  if (e >= E) return;
  int d = dst[e];
  int pos = row_ptr[d] + atomicAdd(&fill[d], 1);
  col_src[pos] = src[e];
}

// ------- W1 cast: W1bf[col][k] = bf16(W1[k][col]), padded to 112 cols -------
__global__ void k_w1cast(const float* __restrict__ W1, unsigned short* __restrict__ W1bf) {
  int i = blockIdx.x * 256 + threadIdx.x;
  if (i >= NPAD * FDIM) return;
  int col = i / FDIM, k = i % FDIM;
  float v = (col < H1) ? W1[k * H1 + col] : 0.f;
  W1bf[i] = (unsigned short)f2bf_bits(v);
}

// ------ GEMM1 (MFMA): t1p[r][c] = bf16( (x @ W1)[r][c] * dinv[r] ) ----------
// BM=128 rows/block, 8 waves, whole K=256 in LDS, XOR-swizzled.
#define BM1 128
__global__ __launch_bounds__(512)
void k_gemm1m(const float* __restrict__ x, const unsigned short* __restrict__ W1bf,
              const float* __restrict__ dinv, unsigned short* __restrict__ t1p, int n) {
  __shared__ unsigned short xs[BM1 * FDIM];    // [row][k], swizzled
  __shared__ unsigned short ws[NPAD * FDIM];   // [col][k], swizzled
  int tid = threadIdx.x;
  int r0 = blockIdx.x * BM1;

  // stage x: 128 rows x 256 k, f32 -> bf16; 8192 float4 chunks, 16/thread
  for (int i = tid; i < BM1 * FDIM / 4; i += 512) {
    int row = i >> 6;          // 64 float4-chunks per row
    int kc = i & 63;           // chunk = 4 k
    int gr = r0 + row;
    float4 v = make_float4(0.f, 0.f, 0.f, 0.f);
    if (gr < n) v = *(const float4*)(x + (size_t)gr * FDIM + kc * 4);
    unsigned addr = (unsigned)(row * 512 + kc * 8) ^ ((unsigned)(row & 7) << 4);
    *(uint2*)((char*)xs + addr) = make_uint2(pack_bf16(v.x, v.y), pack_bf16(v.z, v.w));
  }
  // stage W: 112 cols x 256 k bf16; 3584 16B-chunks, 7/thread
  for (int i = tid; i < NPAD * FDIM / 8; i += 512) {
    int col = i >> 5;          // 32 chunks per col
    int kc = i & 31;           // chunk = 8 k
    uint4 v = *(const uint4*)(W1bf + col * FDIM + kc * 8);
    unsigned addr = (unsigned)(col * 512 + kc * 16) ^ ((unsigned)(col & 7) << 4);
    *(uint4*)((char*)ws + addr) = v;
  }
  __syncthreads();

  int lane = tid & 63, w = tid >> 6;
  int lr = lane & 15, lg = lane >> 4;
  int arow = w * 16 + lr;

  f32x4 acc[7];
#pragma unroll
  for (int nt = 0; nt < 7; nt++) acc[nt] = (f32x4){0.f, 0.f, 0.f, 0.f};

#pragma unroll
  for (int s = 0; s < 8; ++s) {
    int kb = s * 32 + lg * 8;
    bf16x8 a = *(bf16x8*)((char*)xs +
        (((unsigned)(arow * 512 + kb * 2)) ^ ((unsigned)(arow & 7) << 4)));
#pragma unroll
    for (int nt = 0; nt < 7; nt++) {
      int col = nt * 16 + lr;
      bf16x8 b = *(bf16x8*)((char*)ws +
          (((unsigned)(col * 512 + kb * 2)) ^ ((unsigned)(col & 7) << 4)));
      acc[nt] = __builtin_amdgcn_mfma_f32_16x16x32_bf16(a, b, acc[nt], 0, 0, 0);
    }
  }

  // epilogue: D col = lane&15, row = (lane>>4)*4 + r
  float dv[4];
  int rbase = r0 + w * 16 + lg * 4;
#pragma unroll
  for (int r = 0; r < 4; r++) dv[r] = (rbase + r < n) ? dinv[rbase + r] : 0.f;
#pragma unroll
  for (int nt = 0; nt < 7; nt++) {
    int col = nt * 16 + lr;
    if (col < H1) {
#pragma unroll
      for (int r = 0; r < 4; r++) {
        int row = rbase + r;
        if (row < n)
          t1p[(size_t)row * H1 + col] = (unsigned short)f2bf_bits(acc[nt][r] * dv[r]);
      }
    }
  }
}

// ---- agg1: h[d] = bf16(relu(dinv[d]*(sum t1p[s] + t1p[d]) + b1)) -----------
// wave per node; lanes 0..49 each own 2 cols; edge loop unrolled x8 for MLP.
__global__ __launch_bounds__(256)
void k_agg1(const unsigned* __restrict__ t1p, const int* __restrict__ row_ptr,
            const int* __restrict__ col_src, const float* __restrict__ dinv,
            const float* __restrict__ b1, unsigned* __restrict__ h, int n) {
  int wid = (int)((blockIdx.x * (size_t)blockDim.x + threadIdx.x) >> 6);
  if (wid >= n) return;
  int lane = threadIdx.x & 63;
  if (lane >= 50) return;
  int beg = row_ptr[wid], end = row_ptr[wid + 1];
  float a0 = 0.f, a1 = 0.f;
  for (int e = beg; e < end; e += 8) {
    int last = end - 1;
    int i1 = e + 1 < end ? e + 1 : last;
    int i2 = e + 2 < end ? e + 2 : last;
    int i3 = e + 3 < end ? e + 3 : last;
    int i4 = e + 4 < end ? e + 4 : last;
    int i5 = e + 5 < end ? e + 5 : last;
    int i6 = e + 6 < end ? e + 6 : last;
    int i7 = e + 7 < end ? e + 7 : last;
    int s0 = col_src[e],  s1 = col_src[i1], s2 = col_src[i2], s3 = col_src[i3];
    int s4 = col_src[i4], s5 = col_src[i5], s6 = col_src[i6], s7 = col_src[i7];
    unsigned u0 = t1p[(size_t)s0 * 50 + lane];
    unsigned u1 = t1p[(size_t)s1 * 50 + lane];
    unsigned u2 = t1p[(size_t)s2 * 50 + lane];
    unsigned u3 = t1p[(size_t)s3 * 50 + lane];
    unsigned u4 = t1p[(size_t)s4 * 50 + lane];
    unsigned u5 = t1p[(size_t)s5 * 50 + lane];
    unsigned u6 = t1p[(size_t)s6 * 50 + lane];
    unsigned u7 = t1p[(size_t)s7 * 50 + lane];
    a0 += bf_lo(u0); a1 += bf_hi(u0);
    if (e + 1 < end) { a0 += bf_lo(u1); a1 += bf_hi(u1); }
    if (e + 2 < end) { a0 += bf_lo(u2); a1 += bf_hi(u2); }
    if (e + 3 < end) { a0 += bf_lo(u3); a1 += bf_hi(u3); }
    if (e + 4 < end) { a0 += bf_lo(u4); a1 += bf_hi(u4); }
    if (e + 5 < end) { a0 += bf_lo(u5); a1 += bf_hi(u5); }
    if (e + 6 < end) { a0 += bf_lo(u6); a1 += bf_hi(u6); }
    if (e + 7 < end) { a0 += bf_lo(u7); a1 += bf_hi(u7); }
  }
  unsigned su = t1p[(size_t)wid * 50 + lane];
  a0 += bf_lo(su);
  a1 += bf_hi(su);
  float dv = dinv[wid];
  float v0 = fmaxf(dv * a0 + b1[2 * lane], 0.f);
  float v1 = fmaxf(dv * a1 + b1[2 * lane + 1], 0.f);
  h[(size_t)wid * 50 + lane] = pack_bf16(v0, v1);
}

// ------ GEMM2: t2p = bf16( (h @ W2) * dinv )  (N x 100 x 16) ----------------
__global__ __launch_bounds__(256)
void k_gemm2(const unsigned* __restrict__ h, const float* __restrict__ W2,
             const float* __restrict__ dinv, unsigned* __restrict__ t2p, int n) {
  __shared__ alignas(16) float w2s[100][16];
  __shared__ float hs[64][101];
  int tid = threadIdx.x;
  int r0 = blockIdx.x * 64;
  for (int idx = tid; idx < H1 * H2; idx += 256) w2s[idx / 16][idx % 16] = W2[idx];
  for (int idx = tid; idx < 64 * 50; idx += 256) {
    int row = idx / 50, u = idx % 50;
    int gr = r0 + row;
    unsigned v = 0;
    if (gr < n) v = h[(size_t)gr * 50 + u];
    hs[row][2 * u + 0] = bf_lo(v);
    hs[row][2 * u + 1] = bf_hi(v);
  }
  __syncthreads();
  int r = tid & 63, cg = tid >> 6;
  float ax = 0.f, ay = 0.f, az = 0.f, aw = 0.f;
#pragma unroll 4
  for (int k = 0; k < H1; ++k) {
    float a = hs[r][k];
    float4 w = *(const float4*)&w2s[k][cg * 4];
    ax += a * w.x; ay += a * w.y; az += a * w.z; aw += a * w.w;
  }
  int gr = r0 + r;
  if (gr < n) {
    float dv = dinv[gr];
    unsigned u0 = pack_bf16(ax * dv, ay * dv);
    unsigned u1 = pack_bf16(az * dv, aw * dv);
    *(uint2*)(t2p + (size_t)gr * 8 + cg * 2) = make_uint2(u0, u1);
  }
}

// ------- agg2 + bias + relu + row-normalize: emb (N x 16, f32) --------------
__global__ __launch_bounds__(256)
void k_agg2(const unsigned* __restrict__ t2p, const int* __restrict__ row_ptr,
            const int* __restrict__ col_src, const float* __restrict__ dinv,
            const float* __restrict__ b2, float* __restrict__ emb, int n) {
  int wid = (int)((blockIdx.x * (size_t)blockDim.x + threadIdx.x) >> 6);
  if (wid >= n) return;
  int lane = threadIdx.x & 63;
  int es = lane >> 3, c = lane & 7;
  int beg = row_ptr[wid], end = row_ptr[wid + 1];
  float a0 = 0.f, a1 = 0.f;
  for (int e = beg + es; e < end; e += 8) {
    int s = col_src[e];
    unsigned u = t2p[(size_t)s * 8 + c];
    a0 += bf_lo(u);
    a1 += bf_hi(u);
  }
  a0 += __shfl_xor(a0, 8, 64);  a1 += __shfl_xor(a1, 8, 64);
  a0 += __shfl_xor(a0, 16, 64); a1 += __shfl_xor(a1, 16, 64);
  a0 += __shfl_xor(a0, 32, 64); a1 += __shfl_xor(a1, 32, 64);
  unsigned su = t2p[(size_t)wid * 8 + c];
  a0 += bf_lo(su);
  a1 += bf_hi(su);
  float dv = dinv[wid];
  float v0 = fmaxf(dv * a0 + b2[2 * c + 0], 0.f);
  float v1 = fmaxf(dv * a1 + b2[2 * c + 1], 0.f);
  float n2 = v0 * v0 + v1 * v1;
  n2 += __shfl_xor(n2, 1, 64);
  n2 += __shfl_xor(n2, 2, 64);
  n2 += __shfl_xor(n2, 4, 64);
  float scale = 1.f / fmaxf(sqrtf(n2), 1.f);
  if (es == 0) {
    *(float2*)(emb + (size_t)wid * H2 + 2 * c) = make_float2(v0 * scale, v1 * scale);
  }
}

// ---------------- edge scorer ------------------------------------------------
__global__ __launch_bounds__(256)
void k_score(const float* __restrict__ emb, const int* __restrict__ te,
             const float* __restrict__ PI, const float* __restrict__ l1W,
             const float* __restrict__ l1b, const float* __restrict__ lW,
             const float* __restrict__ lb, float* __restrict__ out, int ned) {
  __shared__ alignas(16) float wT[25][44];
  __shared__ float sb1[25], sw2[25];
  for (int idx = threadIdx.x; idx < 41 * 25; idx += blockDim.x) {
    int i = idx / 25, j = idx % 25;
    wT[j][i] = l1W[idx];
  }
  for (int idx = threadIdx.x; idx < 25; idx += blockDim.x) {
    sb1[idx] = l1b[idx];
    sw2[idx] = lW[idx];
  }
  __syncthreads();
  int e = blockIdx.x * blockDim.x + threadIdx.x;
  if (e >= ned) return;
  int u = te[2 * e], v = te[2 * e + 1];
  float f[41];
  const float4* eu = (const float4*)(emb + (size_t)u * H2);
  const float4* ev = (const float4*)(emb + (size_t)v * H2);
#pragma unroll
  for (int q = 0; q < 4; q++) {
    float4 a = eu[q], b = ev[q];
    float dx = a.x - b.x, dy = a.y - b.y, dz = a.z - b.z, dw = a.w - b.w;
    f[q * 4 + 0] = dx * dx; f[q * 4 + 1] = dy * dy;
    f[q * 4 + 2] = dz * dz; f[q * 4 + 3] = dw * dw;
  }
  const float* pi = PI + (size_t)e * 25;
#pragma unroll
  for (int i = 0; i < 25; i++) f[16 + i] = pi[i];
  float acc2 = lb[0];
  for (int j = 0; j < 25; j++) {
    float a = sb1[j];
#pragma unroll
    for (int i = 0; i < 41; i++) a += f[i] * wT[j][i];
    a = (a > 0.f) ? a : 0.2f * a;
    acc2 += a * sw2[j];
  }
  float s = fminf(fabsf(acc2), 40.f);
  float z = 2.f - s;
  out[e] = 1.f / (1.f + __expf(-z));
}

// ---------------- launch -----------------------------------------------------
extern "C" void kernel_launch(void* const* d_in, const int* in_sizes, int n_in,
                              void* d_out, int out_size, void* d_ws, size_t ws_size,
                              hipStream_t stream) {
  const float* x   = (const float*)d_in[0];
  const int*   ei  = (const int*)d_in[1];
  const int*   te  = (const int*)d_in[2];
  const float* PI  = (const float*)d_in[3];
  const float* W1  = (const float*)d_in[4];
  const float* b1  = (const float*)d_in[5];
  const float* W2  = (const float*)d_in[6];
  const float* b2  = (const float*)d_in[7];
  const float* l1W = (const float*)d_in[8];
  const float* l1b = (const float*)d_in[9];
  const float* lW  = (const float*)d_in[10];
  const float* lb  = (const float*)d_in[11];
  float* out = (float*)d_out;

  int h1 = in_sizes[5];            // 100
  int F  = in_sizes[4] / h1;       // 256
  int N  = in_sizes[0] / F;        // 100000
  int E  = in_sizes[1] / 2;        // 1600000
  int ED = in_sizes[2] / 2;        // 1000000

  const int* src  = ei;
  const int* dstp = ei + E;

  size_t off = 0;
  auto alloc = [&](size_t bytes) -> void* {
    void* p = (char*)d_ws + off;
    off += (bytes + 255) & ~(size_t)255;
    return p;
  };
  int*            deg     = (int*)alloc((size_t)N * 4);
  float*          dinv    = (float*)alloc((size_t)N * 4);
  int*            row_ptr = (int*)alloc((size_t)(N + 1) * 4);
  int*            fill    = (int*)alloc((size_t)N * 4);
  int*            psum    = (int*)alloc(512 * 4);
  int*            col_src = (int*)alloc((size_t)E * 4);
  unsigned short* W1bf    = (unsigned short*)alloc((size_t)NPAD * FDIM * 2);
  unsigned*       t1p     = (unsigned*)alloc((size_t)N * 50 * 4);  // bf16 x2 packed
  unsigned*       h       = (unsigned*)alloc((size_t)N * 50 * 4);
  unsigned*       t2p     = (unsigned*)alloc((size_t)N * 8 * 4);
  float*          emb     = (float*)alloc((size_t)N * H2 * 4);

  int nb = (N + 255) / 256;

  hipMemsetAsync(deg, 0, (size_t)N * 4, stream);
  k_hist<<<(E + 255) / 256, 256, 0, stream>>>(dstp, deg, E);
  k_dinv<<<(N + 255) / 256, 256, 0, stream>>>(deg, dinv, N);
  k_scanA<<<nb, 256, 0, stream>>>(deg, row_ptr, psum, N);
  k_scanB<<<1, 512, 0, stream>>>(psum, nb);
  k_scanC<<<nb, 256, 0, stream>>>(row_ptr, psum, N, E);
  hipMemsetAsync(fill, 0, (size_t)N * 4, stream);
  k_scatter<<<(E + 255) / 256, 256, 0, stream>>>(src, dstp, row_ptr, fill, col_src, E);
  k_w1cast<<<(NPAD * FDIM + 255) / 256, 256, 0, stream>>>(W1, W1bf);
  k_gemm1m<<<(N + BM1 - 1) / BM1, 512, 0, stream>>>(x, W1bf, dinv, (unsigned short*)t1p, N);
  k_agg1<<<(int)(((size_t)N * 64 + 255) / 256), 256, 0, stream>>>(t1p, row_ptr, col_src, dinv, b1, h, N);
  k_gemm2<<<(N + 63) / 64, 256, 0, stream>>>(h, W2, dinv, t2p, N);
  k_agg2<<<(int)(((size_t)N * 64 + 255) / 256), 256, 0, stream>>>(t2p, row_ptr, col_src, dinv, b2, emb, N);
  k_score<<<(ED + 255) / 256, 256, 0, stream>>>(emb, te, PI, l1W, l1b, lW, lb, out, ED);
}